// Round 3
// baseline (9137.349 us; speedup 1.0000x reference)
//
#include <hip/hip_runtime.h>

#define SEQ 1024
#define NB  64
#define NI  256
#define NH  256

typedef __bf16 bf16x8 __attribute__((ext_vector_type(8)));
typedef float  f32x4  __attribute__((ext_vector_type(4)));
typedef unsigned int u32x4 __attribute__((ext_vector_type(4)));
typedef unsigned short u16;
typedef unsigned int u32;

static __device__ __forceinline__ u16 f2bf(float f) {
    u32 u = __float_as_uint(f);
    u += 0x7fffu + ((u >> 16) & 1u);
    return (u16)(u >> 16);
}
static __device__ __forceinline__ float sigm_(float x) {
    return __builtin_amdgcn_rcpf(1.0f + __builtin_amdgcn_exp2f(-1.4426950408889634f * x));
}
static __device__ __forceinline__ float tanh_(float x) {
    return 1.0f - 2.0f * __builtin_amdgcn_rcpf(__builtin_amdgcn_exp2f(2.8853900817779268f * x) + 1.0f);
}

// ---- fast-path primitives (semantics VERIFIED at runtime by self-test) ----
static __device__ __forceinline__ void st_u32_sc0(u32* p, u32 v) {
    asm volatile("global_store_dword %0, %1, off sc0" :: "v"(p), "v"(v) : "memory");
}
static __device__ __forceinline__ u32 ld_u32_sc0(const u32* p) {
    u32 v;
    asm volatile("global_load_dword %0, %1, off sc0\n\ts_waitcnt vmcnt(0)"
                 : "=&v"(v) : "v"(p) : "memory");
    return v;
}
// read 8 flags spaced 256B apart, one vmcnt, return min
static __device__ __forceinline__ u32 min8_sc0(const u32* p) {
    u32 a0,a1,a2,a3,a4,a5,a6,a7;
    asm volatile(
        "global_load_dword %0, %8, off sc0\n\t"
        "global_load_dword %1, %8, off offset:256 sc0\n\t"
        "global_load_dword %2, %8, off offset:512 sc0\n\t"
        "global_load_dword %3, %8, off offset:768 sc0\n\t"
        "global_load_dword %4, %8, off offset:1024 sc0\n\t"
        "global_load_dword %5, %8, off offset:1280 sc0\n\t"
        "global_load_dword %6, %8, off offset:1536 sc0\n\t"
        "global_load_dword %7, %8, off offset:1792 sc0\n\t"
        "s_waitcnt vmcnt(0)"
        : "=&v"(a0),"=&v"(a1),"=&v"(a2),"=&v"(a3),
          "=&v"(a4),"=&v"(a5),"=&v"(a6),"=&v"(a7)
        : "v"(p) : "memory");
    u32 m0 = a0 < a1 ? a0 : a1,  m1 = a2 < a3 ? a2 : a3;
    u32 m2 = a4 < a5 ? a4 : a5,  m3 = a6 < a7 ? a6 : a7;
    u32 m4 = m0 < m1 ? m0 : m1,  m5 = m2 < m3 ? m2 : m3;
    return m4 < m5 ? m4 : m5;
}
static __device__ __forceinline__ void ld32_sc0(const void* p, f32x4* a, f32x4* b) {
    asm volatile("global_load_dwordx4 %0, %2, off sc0\n\t"
                 "global_load_dwordx4 %1, %2, off offset:16 sc0\n\t"
                 "s_waitcnt vmcnt(0)"
                 : "=&v"(*a), "=&v"(*b) : "v"(p) : "memory");
}
static __device__ __forceinline__ u32 pat(int g, int role, int r, int i) {
    return 0x9E3779B9u * (u32)(g * 1031 + role * 131 + r * 17 + i) ^ 0xA5A5A5A5u;
}

// ctl layout (u32 idx): [0..63] slow counters (g*32) | [64..127] vcnt | [128..143] xtab
// [160..255] vote done/pass | [512..1535] fast flags (256B/WG) | [2048..3071] test lines
// mex at d_ws+16KB: 2 parity x 2 group x 32 x 256 bf16
__global__ __launch_bounds__(512, 2)
void nas_scan(const float* __restrict__ xg, const float* __restrict__ wih,
              const float* __restrict__ whh, float* __restrict__ out,
              u32* ctl, u16* mex)
{
    __shared__ __align__(16) unsigned char xbuf[32 * 512];
    __shared__ __align__(16) unsigned char mbuf[32 * 512];
    __shared__ float gbuf[32 * 256];
    __shared__ int sh_fast;

    const int bid = blockIdx.x;
    if ((bid & 7) > 1) return;       // 48 of 64 WGs exit
    const int g    = bid & 7;        // batch-group (rows g*32..+32); bid%8 ~ XCD
    const int role = bid >> 3;       // 0..7 column slice (32 cols)
    const int c0   = role * 32;

    const int t    = threadIdx.x;
    const int lane = t & 63;
    const int wave = t >> 6;
    const int fr   = lane & 15;
    const int fq   = lane >> 4;
    const int ch   = wave & 1;
    const int Gh   = wave >> 1;

    u32* scnt  = ctl + g * 32;
    u32* vcnt  = ctl + 64 + g * 32;
    u32* xtab  = ctl + 128 + g * 8;
    u32* vdone = ctl + 160 + g * 32;
    u32* vpass = ctl + 224 + g * 16;
    u32* flagb = ctl + 512 + g * 512;          // 8 flags, 64 u32 (256B) apart
    u32* myflg = flagb + role * 64;
    u32* tl    = ctl + 2048 + g * 512;         // 8 test lines, 256B apart

    // ---- phase 0: placement check + coherence SELF-TEST + agent-scope vote ----
    u32 xcc;
    asm volatile("s_getreg_b32 %0, hwreg(HW_REG_XCC_ID)" : "=s"(xcc));
    if (t == 0) {
        __hip_atomic_store(&xtab[role], xcc + 1u, __ATOMIC_RELEASE, __HIP_MEMORY_SCOPE_AGENT);
        __hip_atomic_fetch_add(vcnt, 1u, __ATOMIC_RELEASE, __HIP_MEMORY_SCOPE_AGENT);
        while (__hip_atomic_load(vcnt, __ATOMIC_RELAXED, __HIP_MEMORY_SCOPE_AGENT) < 8u)
            __builtin_amdgcn_s_sleep(8);
        __builtin_amdgcn_fence(__ATOMIC_ACQUIRE, "agent");
        u32 x0 = __hip_atomic_load(&xtab[0], __ATOMIC_RELAXED, __HIP_MEMORY_SCOPE_AGENT);
        int fail = 0;
        for (int r = 1; r < 8; ++r)
            fail |= (__hip_atomic_load(&xtab[r], __ATOMIC_RELAXED, __HIP_MEMORY_SCOPE_AGENT) != x0);

        // self-test: 3 rounds of the exact fast-path ops on the SAME addresses
        for (int r = 1; r <= 3 && !fail; ++r) {
            u32* ml = tl + role * 64;
            for (int i = 0; i < 16; ++i) ml[i] = pat(g, role, r, i); // plain stores = data path
            asm volatile("s_waitcnt vmcnt(0)" ::: "memory");
            st_u32_sc0(ml + 16, (u32)r);                            // flag path
            for (int rr = 0; rr < 8 && !fail; ++rr) {               // poll path (bounded)
                int iter = 0;
                while (ld_u32_sc0(tl + rr * 64 + 16) < (u32)r) {
                    if (++iter > (1 << 16)) { fail = 1; break; }
                }
            }
            for (int rr = 0; rr < 8 && !fail; ++rr)                 // data read path
                for (int i = 0; i < 16; ++i)
                    if (ld_u32_sc0(tl + rr * 64 + i) != pat(g, rr, r, i)) { fail = 1; break; }
        }

        if (!fail) __hip_atomic_fetch_add(vpass, 1u, __ATOMIC_RELEASE, __HIP_MEMORY_SCOPE_AGENT);
        __hip_atomic_fetch_add(vdone, 1u, __ATOMIC_RELEASE, __HIP_MEMORY_SCOPE_AGENT);
        while (__hip_atomic_load(vdone, __ATOMIC_RELAXED, __HIP_MEMORY_SCOPE_AGENT) < 8u)
            __builtin_amdgcn_s_sleep(8);
        __builtin_amdgcn_fence(__ATOMIC_ACQUIRE, "agent");
        sh_fast = (__hip_atomic_load(vpass, __ATOMIC_RELAXED, __HIP_MEMORY_SCOPE_AGENT) == 8u);
    }
    __syncthreads();
    const bool fastp = (sh_fast != 0);

    // ---- weight B-fragments into registers (128 VGPRs/wave) ----
    bf16x8 wfih[2][8], wfhh[2][8];
#pragma unroll
    for (int gi = 0; gi < 2; ++gi) {
        const int gg = Gh * 2 + gi;
#pragma unroll
        for (int ks = 0; ks < 8; ++ks) {
            bf16x8 a, b;
#pragma unroll
            for (int j = 0; j < 8; ++j) {
                const int idx = (gg * NH + ks * 32 + fq * 8 + j) * NH + (c0 + ch * 16 + fr);
                a[j] = (__bf16)wih[idx];
                b[j] = (__bf16)whh[idx];
            }
            wfih[gi][ks] = a;
            wfhh[gi][ks] = b;
        }
    }

    const f32x4 fzero = {0.f, 0.f, 0.f, 0.f};
    *(f32x4*)(mbuf + t * 32)      = fzero;
    *(f32x4*)(mbuf + t * 32 + 16) = fzero;

    // x addressing: thread t -> row xr, cols xc..xc+15
    const int xr = t >> 4;
    const int xc = (t & 15) * 16;
    const float* xbase = xg + (size_t)(g * 32 + xr) * NI + xc;
    const unsigned sbase = (unsigned)xr * 512u + (unsigned)xc * 2u;
    const unsigned sswz  = ((unsigned)xr & 7u) << 4;

    f32x4 xp[4];
#pragma unroll
    for (int i = 0; i < 4; ++i) xp[i] = *(const f32x4*)(xbase + i * 4);
    {
        u32 w[8];
#pragma unroll
        for (int jj = 0; jj < 8; ++jj) {
            const float a = xp[jj >> 1][(jj & 1) * 2 + 0];
            const float b = xp[jj >> 1][(jj & 1) * 2 + 1];
            w[jj] = (u32)f2bf(a) | ((u32)f2bf(b) << 16);
        }
        u32x4 lo = {w[0], w[1], w[2], w[3]}, hi = {w[4], w[5], w[6], w[7]};
        *(u32x4*)(xbuf + ((sbase + 0u)  ^ sswz)) = lo;
        *(u32x4*)(xbuf + ((sbase + 16u) ^ sswz)) = hi;
    }
    __syncthreads();

    const unsigned aswz = ((unsigned)fr & 7u) << 4;
    const unsigned ab0  = (unsigned)fr * 512u + (unsigned)fq * 16u;
    const unsigned ab1  = (unsigned)(16 + fr) * 512u + (unsigned)fq * 16u;

    f32x4 accx[2][2];
#pragma unroll
    for (int m = 0; m < 2; ++m)
#pragma unroll
        for (int gi = 0; gi < 2; ++gi) accx[m][gi] = fzero;
#pragma unroll
    for (int ks = 0; ks < 8; ++ks) {
        bf16x8 a0 = *(const bf16x8*)(xbuf + ((ab0 + ks * 64u) ^ aswz));
        bf16x8 a1 = *(const bf16x8*)(xbuf + ((ab1 + ks * 64u) ^ aswz));
#pragma unroll
        for (int gi = 0; gi < 2; ++gi) {
            accx[0][gi] = __builtin_amdgcn_mfma_f32_16x16x32_bf16(a0, wfih[gi][ks], accx[0][gi], 0, 0, 0);
            accx[1][gi] = __builtin_amdgcn_mfma_f32_16x16x32_bf16(a1, wfih[gi][ks], accx[1][gi], 0, 0, 0);
        }
    }
#pragma unroll
    for (int i = 0; i < 4; ++i) xp[i] = *(const f32x4*)(xbase + (size_t)(NB * NI) + i * 4);

    const int r_own = t >> 4;
    const int cp    = t & 15;
    float cA = 0.0f, cB = 0.0f;

    for (int s = 0; s < SEQ; ++s) {
        // ---- acc = accx + m * Whh ----
        f32x4 acc[2][2];
#pragma unroll
        for (int m = 0; m < 2; ++m)
#pragma unroll
            for (int gi = 0; gi < 2; ++gi) acc[m][gi] = accx[m][gi];
#pragma unroll
        for (int ks = 0; ks < 8; ++ks) {
            bf16x8 a0 = *(const bf16x8*)(mbuf + ((ab0 + ks * 64u) ^ aswz));
            bf16x8 a1 = *(const bf16x8*)(mbuf + ((ab1 + ks * 64u) ^ aswz));
#pragma unroll
            for (int gi = 0; gi < 2; ++gi) {
                acc[0][gi] = __builtin_amdgcn_mfma_f32_16x16x32_bf16(a0, wfhh[gi][ks], acc[0][gi], 0, 0, 0);
                acc[1][gi] = __builtin_amdgcn_mfma_f32_16x16x32_bf16(a1, wfhh[gi][ks], acc[1][gi], 0, 0, 0);
            }
        }

        // ---- gates -> LDS ----
#pragma unroll
        for (int m = 0; m < 2; ++m)
#pragma unroll
            for (int gi = 0; gi < 2; ++gi) {
                const int colw = (Gh * 2 + gi) * 32 + ch * 16 + fr;
#pragma unroll
                for (int j = 0; j < 4; ++j)
                    gbuf[(m * 16 + fq * 4 + j) * 256 + colw] = acc[m][gi][j];
            }
        __syncthreads(); // A

        // ---- NAS cell ----
        float nm0, nm1;
        {
            float nc[2], nm[2];
            const float* gb = gbuf + r_own * 256 + cp * 2;
#pragma unroll
            for (int e = 0; e < 2; ++e) {
                const float q0 = gb[0 * 32 + e], q1 = gb[1 * 32 + e], q2 = gb[2 * 32 + e], q3 = gb[3 * 32 + e];
                const float q4 = gb[4 * 32 + e], q5 = gb[5 * 32 + e], q6 = gb[6 * 32 + e], q7 = gb[7 * 32 + e];
                const float l10 = sigm_(q0);
                const float l11 = fmaxf(q1, 0.0f);
                const float l12 = sigm_(q2);
                const float l13 = fmaxf(q3, 0.0f);
                const float l14 = tanh_(q4);
                const float l15 = sigm_(q5);
                const float l16 = tanh_(q6);
                const float l17 = sigm_(q7);
                const float l20 = tanh_(l10 * l11);
                const float l21 = tanh_(l12 + l13);
                const float l22 = tanh_(l14 * l15);
                const float l23 = sigm_(l16 + l17);
                const float cold = (e == 0) ? cA : cB;
                const float l20v = tanh_(l20 + cold);
                const float ncv  = l20v * l21;
                const float l31  = tanh_(l22 + l23);
                nc[e] = ncv;
                nm[e] = tanh_(ncv * l31);
            }
            cA = nc[0]; cB = nc[1];
            nm0 = nm[0]; nm1 = nm[1];
        }

        if (s == SEQ - 1) {
            const int obase = (g * 32 + r_own) * NH + c0 + cp * 2;
            out[obase + 0] = cA + nm0;
            out[obase + 1] = cB + nm1;
        } else {
            // ---- publish slice ----
            u16* mexb = mex + (size_t)(s & 1) * 16384 + (size_t)g * 8192;
            *(u32*)(mexb + r_own * 256 + c0 + cp * 2) =
                (u32)f2bf(nm0) | ((u32)f2bf(nm1) << 16);
            __syncthreads(); // B: all threads' stores complete (vmcnt 0)

            if (t == 0) {
                if (fastp) st_u32_sc0(myflg, (u32)(s + 1));
                else __hip_atomic_fetch_add(scnt, 1u, __ATOMIC_RELEASE, __HIP_MEMORY_SCOPE_AGENT);
            }

            // ---- shadow work: stage x[s+1], project through Wih ----
            {
                u32 w[8];
#pragma unroll
                for (int jj = 0; jj < 8; ++jj) {
                    const float a = xp[jj >> 1][(jj & 1) * 2 + 0];
                    const float b = xp[jj >> 1][(jj & 1) * 2 + 1];
                    w[jj] = (u32)f2bf(a) | ((u32)f2bf(b) << 16);
                }
                u32x4 lo = {w[0], w[1], w[2], w[3]}, hi = {w[4], w[5], w[6], w[7]};
                *(u32x4*)(xbuf + ((sbase + 0u)  ^ sswz)) = lo;
                *(u32x4*)(xbuf + ((sbase + 16u) ^ sswz)) = hi;
            }
            __syncthreads(); // X
#pragma unroll
            for (int m = 0; m < 2; ++m)
#pragma unroll
                for (int gi = 0; gi < 2; ++gi) accx[m][gi] = fzero;
#pragma unroll
            for (int ks = 0; ks < 8; ++ks) {
                bf16x8 a0 = *(const bf16x8*)(xbuf + ((ab0 + ks * 64u) ^ aswz));
                bf16x8 a1 = *(const bf16x8*)(xbuf + ((ab1 + ks * 64u) ^ aswz));
#pragma unroll
                for (int gi = 0; gi < 2; ++gi) {
                    accx[0][gi] = __builtin_amdgcn_mfma_f32_16x16x32_bf16(a0, wfih[gi][ks], accx[0][gi], 0, 0, 0);
                    accx[1][gi] = __builtin_amdgcn_mfma_f32_16x16x32_bf16(a1, wfih[gi][ks], accx[1][gi], 0, 0, 0);
                }
            }
            if (s + 2 < SEQ) {
#pragma unroll
                for (int i = 0; i < 4; ++i)
                    xp[i] = *(const f32x4*)(xbase + (size_t)(s + 2) * (NB * NI) + i * 4);
            }

            // ---- wait for group ----
            if (t == 0) {
                if (fastp) {
                    while (min8_sc0(flagb) < (u32)(s + 1)) {}
                } else {
                    const u32 target = 8u * (u32)(s + 1);
                    while (__hip_atomic_load(scnt, __ATOMIC_RELAXED, __HIP_MEMORY_SCOPE_AGENT) < target)
                        __builtin_amdgcn_s_sleep(1);
                    __builtin_amdgcn_fence(__ATOMIC_ACQUIRE, "agent");
                }
            }
            __syncthreads(); // C

            // ---- restage full m ----
            {
                const u16* ms = mex + (size_t)(s & 1) * 16384 + (size_t)g * 8192;
                const int row  = t >> 4;
                const int colb = (t & 15) * 16;
                f32x4 a, b;
                if (fastp) {
                    ld32_sc0(ms + row * 256 + colb, &a, &b);
                } else {
                    a = *(const f32x4*)(ms + row * 256 + colb);
                    b = *(const f32x4*)(ms + row * 256 + colb + 8);
                }
                const unsigned mb  = (unsigned)row * 512u + (unsigned)colb * 2u;
                const unsigned msz = ((unsigned)row & 7u) << 4;
                *(f32x4*)(mbuf + ((mb + 0u)  ^ msz)) = a;
                *(f32x4*)(mbuf + ((mb + 16u) ^ msz)) = b;
            }
            __syncthreads(); // D
        }
    }
}

__global__ void nas_init(u32* ctl) {
    ctl[blockIdx.x * 256 + threadIdx.x] = 0u;
}

extern "C" void kernel_launch(void* const* d_in, const int* in_sizes, int n_in,
                              void* d_out, int out_size, void* d_ws, size_t ws_size,
                              hipStream_t stream) {
    (void)in_sizes; (void)n_in; (void)out_size; (void)ws_size;
    const float* x   = (const float*)d_in[0];
    const float* wih = (const float*)d_in[1];
    const float* whh = (const float*)d_in[2];
    float* out = (float*)d_out;

    u32* ctl = (u32*)d_ws;                     // 16 KB control
    u16* mex = (u16*)((char*)d_ws + 16384);    // 64 KB m exchange

    nas_init<<<dim3(16), dim3(256), 0, stream>>>(ctl);
    nas_scan<<<dim3(64), dim3(512), 0, stream>>>(x, wih, whh, out, ctl, mex);
}

// Round 4
// 5531.080 us; speedup vs baseline: 1.6520x; 1.6520x over previous
//
#include <hip/hip_runtime.h>

#define SEQ 1024
#define NB  64
#define NI  256
#define NH  256

typedef __bf16 bf16x8 __attribute__((ext_vector_type(8)));
typedef float  f32x4  __attribute__((ext_vector_type(4)));
typedef unsigned int u32x4 __attribute__((ext_vector_type(4)));
typedef unsigned short u16;
typedef unsigned int u32;

static __device__ __forceinline__ u16 f2bf(float f) {
    u32 u = __float_as_uint(f);
    u += 0x7fffu + ((u >> 16) & 1u);
    return (u16)(u >> 16);
}
static __device__ __forceinline__ float sigm_(float x) {
    return __builtin_amdgcn_rcpf(1.0f + __builtin_amdgcn_exp2f(-1.4426950408889634f * x));
}
static __device__ __forceinline__ float tanh_(float x) {
    return 1.0f - 2.0f * __builtin_amdgcn_rcpf(__builtin_amdgcn_exp2f(2.8853900817779268f * x) + 1.0f);
}

// MALL-routed (device-coherent point) data ops: sc0 = bypass L1, sc1 = bypass L2.
// Readers never populate stale L2 copies; writers write through to MALL.
static __device__ __forceinline__ void st_dev_u32(u32* p, u32 v) {
    asm volatile("global_store_dword %0, %1, off sc0 sc1" :: "v"(p), "v"(v) : "memory");
}
// 16 x 16B A-fragment loads (rows fr and 16+fr, ks=0..7), single vmcnt drain.
static __device__ __forceinline__ void ld16_dev(const void* p0, const void* p1, bf16x8 mf[2][8]) {
    asm volatile(
        "global_load_dwordx4 %0, %16, off sc0 sc1\n\t"
        "global_load_dwordx4 %1, %16, off offset:64 sc0 sc1\n\t"
        "global_load_dwordx4 %2, %16, off offset:128 sc0 sc1\n\t"
        "global_load_dwordx4 %3, %16, off offset:192 sc0 sc1\n\t"
        "global_load_dwordx4 %4, %16, off offset:256 sc0 sc1\n\t"
        "global_load_dwordx4 %5, %16, off offset:320 sc0 sc1\n\t"
        "global_load_dwordx4 %6, %16, off offset:384 sc0 sc1\n\t"
        "global_load_dwordx4 %7, %16, off offset:448 sc0 sc1\n\t"
        "global_load_dwordx4 %8, %17, off sc0 sc1\n\t"
        "global_load_dwordx4 %9, %17, off offset:64 sc0 sc1\n\t"
        "global_load_dwordx4 %10, %17, off offset:128 sc0 sc1\n\t"
        "global_load_dwordx4 %11, %17, off offset:192 sc0 sc1\n\t"
        "global_load_dwordx4 %12, %17, off offset:256 sc0 sc1\n\t"
        "global_load_dwordx4 %13, %17, off offset:320 sc0 sc1\n\t"
        "global_load_dwordx4 %14, %17, off offset:384 sc0 sc1\n\t"
        "global_load_dwordx4 %15, %17, off offset:448 sc0 sc1\n\t"
        "s_waitcnt vmcnt(0)"
        : "=&v"(mf[0][0]), "=&v"(mf[0][1]), "=&v"(mf[0][2]), "=&v"(mf[0][3]),
          "=&v"(mf[0][4]), "=&v"(mf[0][5]), "=&v"(mf[0][6]), "=&v"(mf[0][7]),
          "=&v"(mf[1][0]), "=&v"(mf[1][1]), "=&v"(mf[1][2]), "=&v"(mf[1][3]),
          "=&v"(mf[1][4]), "=&v"(mf[1][5]), "=&v"(mf[1][6]), "=&v"(mf[1][7])
        : "v"(p0), "v"(p1) : "memory");
}

// Grid: 32 WGs x 256 threads. WG (g, role): batch-group g (rows g*32..+32),
// column slice role (cols role*16..+16). No XCD placement assumptions:
// all cross-WG traffic goes through the MALL (device coherence point).
__global__ __launch_bounds__(256, 1) __attribute__((amdgpu_waves_per_eu(1, 1)))
void nas_scan(const float* __restrict__ xg, const float* __restrict__ wih,
              const float* __restrict__ whh, float* __restrict__ out,
              u32* ctl, u16* mex)
{
    __shared__ __align__(16) unsigned char xbuf[32 * 512]; // [row][k] bf16, XOR-swizzled
    __shared__ float gbuf[32 * 132];                       // [row][gate*16+col], +4 pad

    const int bid  = blockIdx.x;
    const int g    = bid >> 4;        // batch-group 0/1
    const int role = bid & 15;        // column slice
    const int c0   = role * 16;

    const int t    = threadIdx.x;     // 0..255
    const int lane = t & 63;
    const int wave = t >> 6;          // 0..3; wave = gate-pair owner {2w, 2w+1}
    const int fr   = lane & 15;
    const int fq   = lane >> 4;

    u32* flagb = ctl + g * 1024;      // 16 flags, 256B apart
    u32* myflg = flagb + role * 64;

    // ---- weight B-fragments -> registers (128 VGPRs/wave, pinned by waves_per_eu(1,1)) ----
    // B-frag (16x16x32): lane holds col = lane&15, k = (lane>>4)*8 + j
    bf16x8 wfih[2][8], wfhh[2][8];
#pragma unroll
    for (int gi = 0; gi < 2; ++gi) {
        const int gg = wave * 2 + gi;
#pragma unroll
        for (int ks = 0; ks < 8; ++ks) {
            bf16x8 a, b;
#pragma unroll
            for (int j = 0; j < 8; ++j) {
                const int idx = (gg * NH + ks * 32 + fq * 8 + j) * NH + (c0 + fr);
                a[j] = (__bf16)wih[idx];
                b[j] = (__bf16)whh[idx];
            }
            wfih[gi][ks] = a;
            wfhh[gi][ks] = b;
        }
    }

    // ---- x addressing: thread covers row xr = t>>3, cols (t&7)*32..+31 ----
    const int xr  = t >> 3;
    const int xcb = (t & 7) * 32;
    const float* xbase = xg + (size_t)(g * 32 + xr) * NI + xcb;
    const unsigned sbase = (unsigned)xr * 512u + (unsigned)xcb * 2u;
    const unsigned sswz  = ((unsigned)xr & 7u) << 4;

    f32x4 xp[8];
#pragma unroll
    for (int i = 0; i < 8; ++i) xp[i] = *(const f32x4*)(xbase + i * 4);

    // stage x[0] -> xbuf (bf16, swizzled)
    {
        u32 w[16];
#pragma unroll
        for (int jj = 0; jj < 16; ++jj) {
            const float a = xp[jj >> 1][(jj & 1) * 2 + 0];
            const float b = xp[jj >> 1][(jj & 1) * 2 + 1];
            w[jj] = (u32)f2bf(a) | ((u32)f2bf(b) << 16);
        }
#pragma unroll
        for (int q = 0; q < 4; ++q) {
            u32x4 W = {w[q * 4 + 0], w[q * 4 + 1], w[q * 4 + 2], w[q * 4 + 3]};
            *(u32x4*)(xbuf + ((sbase + (unsigned)q * 16u) ^ sswz)) = W;
        }
    }
    __syncthreads();

    // A-frag LDS offsets: rows fr and 16+fr; (16+fr)&7 == fr&7 -> one swizzle
    const unsigned aswz = ((unsigned)fr & 7u) << 4;
    const unsigned ab0  = (unsigned)fr * 512u + (unsigned)fq * 16u;
    const unsigned ab1  = ab0 + 16u * 512u;

    const f32x4 fzero = {0.f, 0.f, 0.f, 0.f};
    f32x4 accx[2][2];
#pragma unroll
    for (int m = 0; m < 2; ++m)
#pragma unroll
        for (int gi = 0; gi < 2; ++gi) accx[m][gi] = fzero;
#pragma unroll
    for (int ks = 0; ks < 8; ++ks) {
        bf16x8 a0 = *(const bf16x8*)(xbuf + ((ab0 + (unsigned)ks * 64u) ^ aswz));
        bf16x8 a1 = *(const bf16x8*)(xbuf + ((ab1 + (unsigned)ks * 64u) ^ aswz));
#pragma unroll
        for (int gi = 0; gi < 2; ++gi) {
            accx[0][gi] = __builtin_amdgcn_mfma_f32_16x16x32_bf16(a0, wfih[gi][ks], accx[0][gi], 0, 0, 0);
            accx[1][gi] = __builtin_amdgcn_mfma_f32_16x16x32_bf16(a1, wfih[gi][ks], accx[1][gi], 0, 0, 0);
        }
    }
    // prefetch x[1]
#pragma unroll
    for (int i = 0; i < 8; ++i) xp[i] = *(const f32x4*)(xbase + (size_t)(NB * NI) + i * 4);

    // mex: [parity][group][32 rows][256 cols] bf16; per-lane A-frag base addrs
    const u16* mexg  = mex + (size_t)g * 8192;
    const u16* mfp0a = mexg + fr * 256 + fq * 8;          // parity 0, rows 0..15
    const u16* mfp0b = mexg + (16 + fr) * 256 + fq * 8;   // parity 0, rows 16..31
    const u16* mfp1a = mfp0a + 16384;                     // parity 1
    const u16* mfp1b = mfp0b + 16384;

    // cell ownership: row r_own = t>>3, cols {2cp, 2cp+1} of this WG's 16
    const int r_own = t >> 3;
    const int cp    = t & 7;
    float cA = 0.0f, cB = 0.0f;

    for (int s = 0; s < SEQ; ++s) {
        f32x4 acc[2][2];
#pragma unroll
        for (int m = 0; m < 2; ++m)
#pragma unroll
            for (int gi = 0; gi < 2; ++gi) acc[m][gi] = accx[m][gi];

        if (s > 0) {
            // ---- poll: lanes 0..15 watch the 16 WG flags (relaxed agent loads) ----
            const u32* fl = flagb + (lane & 15) * 64;
            while (true) {
                u32 v = __hip_atomic_load(fl, __ATOMIC_RELAXED, __HIP_MEMORY_SCOPE_AGENT);
                if (__all((int)(v >= (u32)s))) break;
            }
            // ---- m A-frags direct from MALL -> 32 MFMAs ----
            bf16x8 mf[2][8];
            if (s & 1) ld16_dev(mfp1a, mfp1b, mf);
            else       ld16_dev(mfp0a, mfp0b, mf);
#pragma unroll
            for (int ks = 0; ks < 8; ++ks) {
#pragma unroll
                for (int gi = 0; gi < 2; ++gi) {
                    acc[0][gi] = __builtin_amdgcn_mfma_f32_16x16x32_bf16(mf[0][ks], wfhh[gi][ks], acc[0][gi], 0, 0, 0);
                    acc[1][gi] = __builtin_amdgcn_mfma_f32_16x16x32_bf16(mf[1][ks], wfhh[gi][ks], acc[1][gi], 0, 0, 0);
                }
            }
        }

        // ---- gates -> LDS (C-frag: row=(lane>>4)*4+j, col=lane&15) ----
#pragma unroll
        for (int m = 0; m < 2; ++m)
#pragma unroll
            for (int gi = 0; gi < 2; ++gi) {
                const int colw = (wave * 2 + gi) * 16 + fr;
#pragma unroll
                for (int j = 0; j < 4; ++j)
                    gbuf[(m * 16 + fq * 4 + j) * 132 + colw] = acc[m][gi][j];
            }
        __syncthreads(); // A

        // ---- NAS cell on 2 owned elements ----
        float nm0, nm1;
        {
            float nc[2], nm[2];
            const float* gb = gbuf + r_own * 132 + cp * 2;
#pragma unroll
            for (int e = 0; e < 2; ++e) {
                const float q0 = gb[0 * 16 + e], q1 = gb[1 * 16 + e], q2 = gb[2 * 16 + e], q3 = gb[3 * 16 + e];
                const float q4 = gb[4 * 16 + e], q5 = gb[5 * 16 + e], q6 = gb[6 * 16 + e], q7 = gb[7 * 16 + e];
                const float l10 = sigm_(q0);
                const float l11 = fmaxf(q1, 0.0f);
                const float l12 = sigm_(q2);
                const float l13 = fmaxf(q3, 0.0f);
                const float l14 = tanh_(q4);
                const float l15 = sigm_(q5);
                const float l16 = tanh_(q6);
                const float l17 = sigm_(q7);
                const float l20 = tanh_(l10 * l11);
                const float l21 = tanh_(l12 + l13);
                const float l22 = tanh_(l14 * l15);
                const float l23 = sigm_(l16 + l17);
                const float cold = (e == 0) ? cA : cB;
                const float l20v = tanh_(l20 + cold);
                const float ncv  = l20v * l21;
                const float l31  = tanh_(l22 + l23);
                nc[e] = ncv;
                nm[e] = tanh_(ncv * l31);
            }
            cA = nc[0]; cB = nc[1];
            nm0 = nm[0]; nm1 = nm[1];
        }

        if (s == SEQ - 1) {
            const int obase = (g * 32 + r_own) * NH + c0 + cp * 2;
            out[obase + 0] = cA + nm0;
            out[obase + 1] = cB + nm1;
        } else {
            // ---- publish new_m slice to MALL (bf16 pair per thread) ----
            u32* mw = (u32*)(mexg + (size_t)((s + 1) & 1) * 16384 + r_own * 256 + c0 + cp * 2);
            st_dev_u32(mw, (u32)f2bf(nm0) | ((u32)f2bf(nm1) << 16));
            asm volatile("s_waitcnt vmcnt(0)" ::: "memory"); // data at MALL before flag
            __syncthreads(); // B: all waves drained
            if (t == 0)
                __hip_atomic_store(myflg, (u32)(s + 1), __ATOMIC_RELAXED, __HIP_MEMORY_SCOPE_AGENT);

            // ---- shadow: stage x[s+1], project through Wih, prefetch x[s+2] ----
            {
                u32 w[16];
#pragma unroll
                for (int jj = 0; jj < 16; ++jj) {
                    const float a = xp[jj >> 1][(jj & 1) * 2 + 0];
                    const float b = xp[jj >> 1][(jj & 1) * 2 + 1];
                    w[jj] = (u32)f2bf(a) | ((u32)f2bf(b) << 16);
                }
#pragma unroll
                for (int q = 0; q < 4; ++q) {
                    u32x4 W = {w[q * 4 + 0], w[q * 4 + 1], w[q * 4 + 2], w[q * 4 + 3]};
                    *(u32x4*)(xbuf + ((sbase + (unsigned)q * 16u) ^ sswz)) = W;
                }
            }
            __syncthreads(); // X
#pragma unroll
            for (int m = 0; m < 2; ++m)
#pragma unroll
                for (int gi = 0; gi < 2; ++gi) accx[m][gi] = fzero;
#pragma unroll
            for (int ks = 0; ks < 8; ++ks) {
                bf16x8 a0 = *(const bf16x8*)(xbuf + ((ab0 + (unsigned)ks * 64u) ^ aswz));
                bf16x8 a1 = *(const bf16x8*)(xbuf + ((ab1 + (unsigned)ks * 64u) ^ aswz));
#pragma unroll
                for (int gi = 0; gi < 2; ++gi) {
                    accx[0][gi] = __builtin_amdgcn_mfma_f32_16x16x32_bf16(a0, wfih[gi][ks], accx[0][gi], 0, 0, 0);
                    accx[1][gi] = __builtin_amdgcn_mfma_f32_16x16x32_bf16(a1, wfih[gi][ks], accx[1][gi], 0, 0, 0);
                }
            }
            if (s + 2 < SEQ) {
#pragma unroll
                for (int i = 0; i < 8; ++i)
                    xp[i] = *(const f32x4*)(xbase + (size_t)(s + 2) * (NB * NI) + i * 4);
            }
        }
    }
}

__global__ void nas_init(u32* ctl) {
    __hip_atomic_store(ctl + blockIdx.x * 256 + threadIdx.x, 0u,
                       __ATOMIC_RELAXED, __HIP_MEMORY_SCOPE_AGENT);
}

extern "C" void kernel_launch(void* const* d_in, const int* in_sizes, int n_in,
                              void* d_out, int out_size, void* d_ws, size_t ws_size,
                              hipStream_t stream) {
    (void)in_sizes; (void)n_in; (void)out_size; (void)ws_size;
    const float* x   = (const float*)d_in[0];
    const float* wih = (const float*)d_in[1];
    const float* whh = (const float*)d_in[2];
    float* out = (float*)d_out;

    u32* ctl = (u32*)d_ws;                    // 8 KB flags (2 groups x 16 x 256B)
    u16* mex = (u16*)((char*)d_ws + 8192);    // 64 KB m exchange (2 parity x 2 group x 32x256 bf16)

    nas_init<<<dim3(8), dim3(256), 0, stream>>>(ctl);
    nas_scan<<<dim3(32), dim3(256), 0, stream>>>(x, wih, whh, out, ctl, mex);
}